// Round 3
// baseline (117.896 us; speedup 1.0000x reference)
//
#include <hip/hip_runtime.h>
#include <math.h>

// Problem: BatchPitNorm1d — B=512, S=2048, F=128
//   bw = sigmoid(bw_param)          [F]
//   u[b,f] = mean_s Phi((x[b,f]-cdf[s,f]) / bw[f])
//   out = ndtri(u)                  -> float32 output [B,F]
#define FDIM 128
#define SDIM 2048
#define BDIM 512
#define PARTS 4                 // S-partitions per block (threads per f)
#define BLOCK (FDIM * PARTS)    // 512 threads = 8 waves

// ---------------- AS241 (Wichura) PPND16 inverse normal CDF, fp64 ----------
// Takes both u and cu = 1-u, each computed with full relative accuracy, so
// both tails stay precise.
__device__ __forceinline__ double ndtri_pair(double u, double cu) {
    double q = u - 0.5;
    if (fabs(q) <= 0.425) {
        double r = 0.180625 - q * q;
        double num = (((((((2.5090809287301226727e3  * r + 3.3430575583588128105e4) * r +
                            6.7265770927008700853e4) * r + 4.5921953931549871457e4) * r +
                            1.3731693765509461125e4) * r + 1.9715909503065514427e3) * r +
                            1.3314166789178437745e2) * r + 3.3871328727963666080e0);
        double den = (((((((5.2264952788528545610e3  * r + 2.8729085735721942674e4) * r +
                            3.9307895800092710610e4) * r + 2.1213794301586595867e4) * r +
                            5.3941960214247511077e3) * r + 6.8718700749205790830e2) * r +
                            4.2313330701600911252e1) * r + 1.0);
        return q * num / den;
    }
    double r = (q < 0.0) ? u : cu;
    r = fmax(r, 1e-300);          // NaN-proofing; analytically unreachable here
    r = sqrt(-log(r));
    double val;
    if (r <= 5.0) {
        r -= 1.6;
        double num = (((((((7.74545014278341407640e-4 * r + 2.27238449892691845833e-2) * r +
                            2.41780725177450611770e-1) * r + 1.27045825245236838258e0) * r +
                            3.64784832476320460504e0)  * r + 5.76949722146069140550e0) * r +
                            4.63033784615654529590e0)  * r + 1.42343711074968357734e0);
        double den = (((((((1.05075007164441684324e-9 * r + 5.47593808499534494600e-4) * r +
                            1.51986665636164571966e-2) * r + 1.48103976427480074590e-1) * r +
                            6.89767334985100004550e-1) * r + 1.67638483018380384940e0) * r +
                            2.05319162663775882187e0)  * r + 1.0);
        val = num / den;
    } else {
        r -= 5.0;
        double num = (((((((2.01033439929228813265e-7 * r + 2.71155556874348757815e-5) * r +
                            1.24266094738807843860e-3) * r + 2.65321895265761230930e-2) * r +
                            2.96560571828504891230e-1) * r + 1.78482653991729133580e0) * r +
                            5.46378491116411436990e0)  * r + 6.65790464350110377720e0);
        double den = (((((((2.04426310338993978564e-15 * r + 1.42151175831644588870e-7) * r +
                            1.84631831751005468180e-5)  * r + 7.86869131145613259100e-4) * r +
                            1.48753612908506148525e-2)  * r + 1.36929880922735805310e-1) * r +
                            5.99832206555887937690e-1)  * r + 1.0);
        val = num / den;
    }
    return (q < 0.0) ? -val : val;
}

// e = 0.5*erfc(a), a>=0, via A&S 7.1.26 (abs err ~7.5e-8). Coeffs pre-halved.
__device__ __forceinline__ float half_erfc(float a) {
    float t  = __builtin_amdgcn_rcpf(fmaf(0.3275911f, a, 1.0f));
    float ex = __expf(-a * a);
    float q  = fmaf(0.53070271450f, t, -0.72657601350f);
    q        = fmaf(q, t,  0.71070687050f);
    q        = fmaf(q, t, -0.14224836800f);
    q        = fmaf(q, t,  0.12741479600f);
    return q * t * ex;
}

__global__ __launch_bounds__(BLOCK) void
pit_kernel(const float* __restrict__ x, const float* __restrict__ cdf,
           const float* __restrict__ bwp, float* __restrict__ out) {
    const int b    = blockIdx.x;
    const int f    = threadIdx.x & (FDIM - 1);
    const int part = threadIdx.x >> 7;   // 0..3

    // scale = inv_bw / sqrt(2); inv_bw = 1/sigmoid(p) = 1 + exp(-p) (exact, no div)
    const float p = bwp[f];
    const float s = (1.0f + __expf(-p)) * 0.70710678118654752f;
    const float xv = x[b * FDIM + f];

    const int chunk = SDIM / PARTS;      // 512 samples per part
    const float* cp = cdf + (part * chunk) * FDIM + f;

    // Phi(z) = (z>=0) ? 1-e : e with e = 0.5*erfc(|z|/sqrt2).
    // Track exact integer npos + signed small-term sum so both tails of u
    // keep full relative precision (ndtri amplifies tail error ~2e4x).
    float acc0 = 0.f, acc1 = 0.f, acc2 = 0.f, acc3 = 0.f;
    int npos = 0;

    for (int i = 0; i < chunk; i += 4) {
        float c0 = cp[0 * FDIM];
        float c1 = cp[1 * FDIM];
        float c2 = cp[2 * FDIM];
        float c3 = cp[3 * FDIM];
        cp += 4 * FDIM;

        float d0 = xv - c0, d1 = xv - c1, d2 = xv - c2, d3 = xv - c3;
        float e0 = half_erfc(fabsf(d0) * s);
        float e1 = half_erfc(fabsf(d1) * s);
        float e2 = half_erfc(fabsf(d2) * s);
        float e3 = half_erfc(fabsf(d3) * s);

        bool p0 = d0 >= 0.f, p1 = d1 >= 0.f, p2 = d2 >= 0.f, p3 = d3 >= 0.f;
        acc0 += p0 ? -e0 : e0;
        acc1 += p1 ? -e1 : e1;
        acc2 += p2 ? -e2 : e2;
        acc3 += p3 ? -e3 : e3;
        npos += (int)p0 + (int)p1 + (int)p2 + (int)p3;
    }

    __shared__ float sacc[PARTS][FDIM];
    __shared__ int   snp[PARTS][FDIM];
    sacc[part][f] = (acc0 + acc1) + (acc2 + acc3);
    snp[part][f]  = npos;
    __syncthreads();

    if (part == 0) {
        double a = (double)sacc[0][f] + (double)sacc[1][f] +
                   (double)sacc[2][f] + (double)sacc[3][f];
        int np = snp[0][f] + snp[1][f] + snp[2][f] + snp[3][f];
        // sum Phi = np + a;  sum (1-Phi) = (SDIM-np) - a
        double u  = ((double)np + a) * (1.0 / SDIM);
        double cu = ((double)(SDIM - np) - a) * (1.0 / SDIM);
        double v  = ndtri_pair(u, cu);
        out[b * FDIM + f] = (float)v;
    }
}

extern "C" void kernel_launch(void* const* d_in, const int* in_sizes, int n_in,
                              void* d_out, int out_size, void* d_ws, size_t ws_size,
                              hipStream_t stream) {
    const float* x   = (const float*)d_in[0];   // [512,128]
    const float* cdf = (const float*)d_in[1];   // [2048,128]
    const float* bwp = (const float*)d_in[2];   // [1,128]
    float* out = (float*)d_out;

    pit_kernel<<<dim3(BDIM), dim3(BLOCK), 0, stream>>>(x, cdf, bwp, out);
}

// Round 4
// 80.369 us; speedup vs baseline: 1.4669x; 1.4669x over previous
//
#include <hip/hip_runtime.h>
#include <math.h>

// BatchPitNorm1d — B=512, S=2048, F=128
//   u[b,f] = mean_s Phi((x[b,f]-cdf[s,f]) / sigmoid(bwp[f]));  out = ndtri(u)
//
// Table method: u(x) per feature is smooth+monotone. Build (u, 1-u, du/dx) on a
// G=128 uniform x-grid per feature (exact Hermite derivatives come free from the
// exp(-z^2/2) already computed in erfc), then cubic-Hermite interpolate at the 512
// actual x values. Evals: G*S*F = 33.5M vs direct B*S*F = 134M (4x).
#define FDIM  128
#define SDIM  2048
#define BDIM  512
#define GPTS  128           // grid points
#define SP    8             // S-partitions across blocks
#define PARTS 4             // S-partitions within block (threads per f)
#define BLOCK1 (FDIM * PARTS)
#define XMIN  (-6.5)
#define XSPAN (13.0)        // grid covers [-6.5, 6.5]; H = XSPAN/(GPTS-1)

// ---------------- AS241 (Wichura) PPND16 inverse normal CDF, fp64 ----------
__device__ __forceinline__ double ndtri_pair(double u, double cu) {
    double q = u - 0.5;
    if (fabs(q) <= 0.425) {
        double r = 0.180625 - q * q;
        double num = (((((((2.5090809287301226727e3  * r + 3.3430575583588128105e4) * r +
                            6.7265770927008700853e4) * r + 4.5921953931549871457e4) * r +
                            1.3731693765509461125e4) * r + 1.9715909503065514427e3) * r +
                            1.3314166789178437745e2) * r + 3.3871328727963666080e0);
        double den = (((((((5.2264952788528545610e3  * r + 2.8729085735721942674e4) * r +
                            3.9307895800092710610e4) * r + 2.1213794301586595867e4) * r +
                            5.3941960214247511077e3) * r + 6.8718700749205790830e2) * r +
                            4.2313330701600911252e1) * r + 1.0);
        return q * num / den;
    }
    double r = (q < 0.0) ? u : cu;
    r = fmax(r, 1e-300);
    r = sqrt(-log(r));
    double val;
    if (r <= 5.0) {
        r -= 1.6;
        double num = (((((((7.74545014278341407640e-4 * r + 2.27238449892691845833e-2) * r +
                            2.41780725177450611770e-1) * r + 1.27045825245236838258e0) * r +
                            3.64784832476320460504e0)  * r + 5.76949722146069140550e0) * r +
                            4.63033784615654529590e0)  * r + 1.42343711074968357734e0);
        double den = (((((((1.05075007164441684324e-9 * r + 5.47593808499534494600e-4) * r +
                            1.51986665636164571966e-2) * r + 1.48103976427480074590e-1) * r +
                            6.89767334985100004550e-1) * r + 1.67638483018380384940e0) * r +
                            2.05319162663775882187e0)  * r + 1.0);
        val = num / den;
    } else {
        r -= 5.0;
        double num = (((((((2.01033439929228813265e-7 * r + 2.71155556874348757815e-5) * r +
                            1.24266094738807843860e-3) * r + 2.65321895265761230930e-2) * r +
                            2.96560571828504891230e-1) * r + 1.78482653991729133580e0) * r +
                            5.46378491116411436990e0)  * r + 6.65790464350110377720e0);
        double den = (((((((2.04426310338993978564e-15 * r + 1.42151175831644588870e-7) * r +
                            1.84631831751005468180e-5)  * r + 7.86869131145613259100e-4) * r +
                            1.48753612908506148525e-2)  * r + 1.36929880922735805310e-1) * r +
                            5.99832206555887937690e-1)  * r + 1.0);
        val = num / den;
    }
    return (q < 0.0) ? -val : val;
}

// e = 0.5*erfc(a), a>=0, A&S 7.1.26 (abs err ~7.5e-8); also returns ex=exp(-a^2)
__device__ __forceinline__ float half_erfc_ex(float a, float& ex_out) {
    float t  = __builtin_amdgcn_rcpf(fmaf(0.3275911f, a, 1.0f));
    float ex = __expf(-a * a);
    ex_out = ex;
    float q  = fmaf(0.53070271450f, t, -0.72657601350f);
    q        = fmaf(q, t,  0.71070687050f);
    q        = fmaf(q, t, -0.14224836800f);
    q        = fmaf(q, t,  0.12741479600f);
    return q * t * ex;
}

// ---------- K1: per-(gridpoint, S-chunk) partial sums -----------------------
// blockIdx.x = g*SP + sp;  512 threads = 128 f x 4 parts; 64 samples/thread.
__global__ __launch_bounds__(BLOCK1) void build_kernel(
    const float* __restrict__ cdf, const float* __restrict__ bwp,
    float* __restrict__ accP, float* __restrict__ dacP, int* __restrict__ npP)
{
    const int g    = blockIdx.x >> 3;
    const int sp   = blockIdx.x & (SP - 1);
    const int f    = threadIdx.x & (FDIM - 1);
    const int part = threadIdx.x >> 7;

    const float p = bwp[f];
    const float s = (1.0f + __expf(-p)) * 0.70710678118654752f;
    const float xg = (float)(XMIN + (double)g * (XSPAN / (GPTS - 1)));

    const int chunk = SDIM / SP / PARTS;           // 64 samples
    const int base  = sp * (SDIM / SP) + part * chunk;
    const float* cp = cdf + base * FDIM + f;

    float acc0 = 0.f, acc1 = 0.f, acc2 = 0.f, acc3 = 0.f;
    float dac = 0.f;
    int npos = 0;

    for (int i = 0; i < chunk; i += 4) {
        float c0 = cp[0 * FDIM];
        float c1 = cp[1 * FDIM];
        float c2 = cp[2 * FDIM];
        float c3 = cp[3 * FDIM];
        cp += 4 * FDIM;

        float d0 = xg - c0, d1 = xg - c1, d2 = xg - c2, d3 = xg - c3;
        float x0, x1, x2, x3;
        float e0 = half_erfc_ex(fabsf(d0) * s, x0);
        float e1 = half_erfc_ex(fabsf(d1) * s, x1);
        float e2 = half_erfc_ex(fabsf(d2) * s, x2);
        float e3 = half_erfc_ex(fabsf(d3) * s, x3);

        bool p0 = d0 >= 0.f, p1 = d1 >= 0.f, p2 = d2 >= 0.f, p3 = d3 >= 0.f;
        acc0 += p0 ? -e0 : e0;
        acc1 += p1 ? -e1 : e1;
        acc2 += p2 ? -e2 : e2;
        acc3 += p3 ? -e3 : e3;
        npos += (int)p0 + (int)p1 + (int)p2 + (int)p3;
        dac  += (x0 + x1) + (x2 + x3);             // sum exp(-z^2/2) for du/dx
    }

    __shared__ float sacc[PARTS][FDIM];
    __shared__ float sdac[PARTS][FDIM];
    __shared__ int   snp[PARTS][FDIM];
    sacc[part][f] = (acc0 + acc1) + (acc2 + acc3);
    sdac[part][f] = dac;
    snp[part][f]  = npos;
    __syncthreads();

    if (part == 0) {
        float a  = (sacc[0][f] + sacc[1][f]) + (sacc[2][f] + sacc[3][f]);
        float da = (sdac[0][f] + sdac[1][f]) + (sdac[2][f] + sdac[3][f]);
        int   np = snp[0][f] + snp[1][f] + snp[2][f] + snp[3][f];
        const int o = blockIdx.x * FDIM + f;       // (g*SP+sp)*FDIM + f
        accP[o] = a;
        dacP[o] = da;
        npP[o]  = np;
    }
}

// ---------- K2: reduce SP partials -> fp64 table (u, 1-u, du/dx) ------------
__global__ __launch_bounds__(256) void table_kernel(
    const float* __restrict__ accP, const float* __restrict__ dacP,
    const int* __restrict__ npP, const float* __restrict__ bwp,
    double* __restrict__ Tu, double* __restrict__ Tcu, double* __restrict__ Td)
{
    const int idx = blockIdx.x * 256 + threadIdx.x;   // [0, GPTS*FDIM)
    const int g = idx >> 7;
    const int f = idx & (FDIM - 1);
    (void)g;

    double a = 0.0, da = 0.0;
    int np = 0;
    #pragma unroll
    for (int sp = 0; sp < SP; ++sp) {
        const int o = ((idx >> 7) * SP + sp) * FDIM + f;
        a  += (double)accP[o];
        da += (double)dacP[o];
        np += npP[o];
    }
    // sum Phi = np + a ;  sum (1-Phi) = (S-np) - a
    const double invS = 1.0 / (double)SDIM;
    double u  = ((double)np + a) * invS;
    double cu = ((double)(SDIM - np) - a) * invS;
    double invbw = 1.0 + exp(-(double)bwp[f]);
    // du/dx = (1/(S*bw*sqrt(2pi))) * sum exp(-z^2/2)
    double du = da * invbw * (1.0 / ((double)SDIM * 2.5066282746310002));
    Tu[idx]  = u;
    Tcu[idx] = cu;
    Td[idx]  = du;
}

// ---------- K3: cubic Hermite interpolation + ndtri -------------------------
__global__ __launch_bounds__(256) void interp_kernel(
    const float* __restrict__ x,
    const double* __restrict__ Tu, const double* __restrict__ Tcu,
    const double* __restrict__ Td, float* __restrict__ out)
{
    const int idx = blockIdx.x * 256 + threadIdx.x;   // b*FDIM + f
    const int f = idx & (FDIM - 1);

    const double H = XSPAN / (GPTS - 1);
    double t = ((double)x[idx] - XMIN) * ((GPTS - 1) / XSPAN);
    t = fmin(fmax(t, 0.0), (double)(GPTS - 1));
    int i = (int)t;
    if (i > GPTS - 2) i = GPTS - 2;
    double w = t - (double)i;

    const int o0 = i * FDIM + f;
    const int o1 = o0 + FDIM;
    double u0 = Tu[o0],  u1 = Tu[o1];
    double c0 = Tcu[o0], c1 = Tcu[o1];
    double m0 = Td[o0],  m1 = Td[o1];

    double w2 = w * w, w3 = w2 * w;
    double h00 = 2.0 * w3 - 3.0 * w2 + 1.0;
    double h10 = w3 - 2.0 * w2 + w;
    double h01 = 3.0 * w2 - 2.0 * w3;
    double h11 = w3 - w2;
    double dterm = H * (h10 * m0 + h11 * m1);
    double u  = h00 * u0 + h01 * u1 + dterm;
    double cu = h00 * c0 + h01 * c1 - dterm;

    out[idx] = (float)ndtri_pair(u, cu);
}

extern "C" void kernel_launch(void* const* d_in, const int* in_sizes, int n_in,
                              void* d_out, int out_size, void* d_ws, size_t ws_size,
                              hipStream_t stream) {
    const float* x   = (const float*)d_in[0];   // [512,128]
    const float* cdf = (const float*)d_in[1];   // [2048,128]
    const float* bwp = (const float*)d_in[2];   // [1,128]
    float* out = (float*)d_out;

    // workspace layout (8B-aligned): doubles first, then floats/ints
    const size_t GF   = (size_t)GPTS * FDIM;        // 16384
    const size_t GSPF = (size_t)GPTS * SP * FDIM;   // 131072
    char* wsb = (char*)d_ws;
    double* Tu   = (double*)wsb;                    // GF*8  = 128KB
    double* Tcu  = Tu + GF;                         // 128KB
    double* Td   = Tcu + GF;                        // 128KB
    float*  accP = (float*)(Td + GF);               // GSPF*4 = 512KB
    float*  dacP = accP + GSPF;                     // 512KB
    int*    npP  = (int*)(dacP + GSPF);             // 512KB  -> total ~1.9MB

    build_kernel<<<dim3(GPTS * SP), dim3(BLOCK1), 0, stream>>>(cdf, bwp, accP, dacP, npP);
    table_kernel<<<dim3(GF / 256), dim3(256), 0, stream>>>(accP, dacP, npP, bwp, Tu, Tcu, Td);
    interp_kernel<<<dim3((BDIM * FDIM) / 256), dim3(256), 0, stream>>>(x, Tu, Tcu, Td, out);
}